// Round 1
// baseline (420.842 us; speedup 1.0000x reference)
//
#include <hip/hip_runtime.h>
#include <hip/hip_bf16.h>

// Problem constants (match reference)
#define NB   8
#define NN   256
#define NM   32
#define NHW  32768

// Grid: NB(8) x CCH(64) = 512 blocks (2/CU), 512 threads = 8 waves.
// Block owns ALL n=256 and a c-slab of 512; kstep = 32 c, double-buffered LDS.
// Wave w owns n in [32w, 32w+32) exclusively -> no cross-wave reduction.
#define CCH    64
#define CSLAB  (NHW / CCH)     // 512 c per block
#define KC     32              // c per kstep
#define KSTEPS (CSLAB / KC)    // 16

// ws layout (floats) -- every cell written exactly once, no memset needed
#define OFF_DXP  0                           // [CCH][NB][NN][NM]
#define SZ_DXP   (CCH*NB*NN*NM)
#define OFF_DSP  (OFF_DXP + SZ_DXP)
#define OFF_SNP  (OFF_DSP + SZ_DXP)          // [CCH][NB][NN]
#define SZ_SNP   (CCH*NB*NN)
#define OFF_SSP  (OFF_SNP + SZ_SNP)
#define OFF_STGT (OFF_SSP + SZ_SNP)          // [CCH][NB][NM]

typedef _Float16 half8 __attribute__((ext_vector_type(8)));
typedef float    f32x4 __attribute__((ext_vector_type(4)));

#define MFMA16(a, b, c) __builtin_amdgcn_mfma_f32_16x16x32_f16(a, b, c, 0, 0, 0)

typedef const __attribute__((address_space(1))) unsigned int* gp_t;
typedef __attribute__((address_space(3))) unsigned int*       lp_t;

// Stage one 1KB X row (256 f32) into LDS, ROTATED by `rot` floats (m173
// pattern: LDS dest stays linear as global_load_lds requires; the SOURCE is
// pre-swizzled).  LDS col k holds X[(k - rot) & 255]; readers use col
// (n + rot) & 255.  rot = 8*(row>>3) spreads the 4 quads' column reads across
// all 32 banks (perfect 2-way, free) instead of 16 banks (4-way, 1.58x).
__device__ __forceinline__ void stage_row(const float* gsrc, float* ldst,
                                          int lane, int rot) {
    const int src = ((lane << 2) - rot) & 255;
#if __has_builtin(__builtin_amdgcn_global_load_lds)
    __builtin_amdgcn_global_load_lds((gp_t)(const void*)(gsrc + src),
                                     (lp_t)(void*)ldst, 16, 0, 0);
#else
    float4 v = *(const float4*)(gsrc + src);
    *(float4*)(ldst + lane * 4) = v;
#endif
}

// ---------------------------------------------------------------------------
// Fragment-direct MFMA contraction, 256n x 32m per block, LDS-staged X.
//   Dx[n,m] = sum_c x*t        Ds[n,m] = sum_c sigmoid(x)*t
//   Sn[n]   = sum_c (x + softplus(-x))   Ss[n] = sum_c sigmoid(x)
//   St[m]   = sum_c t
// A-frag (16x16x32 f16): lane holds A[row=lane&15][k=(lane>>4)*8+j]
// B-frag:                lane holds B[col=lane&15][k=(lane>>4)*8+j]
// D:                     lane reg r -> row=(lane>>4)*4+r, col=lane&15
__global__ __launch_bounds__(512, 4) void cost_main(
    const float* __restrict__ X,   // [NB][NHW][NN]
    const float* __restrict__ T,   // [NB][NM][NHW]
    float* __restrict__ ws) {
    const int blk = blockIdx.x;
    const int b   = blk & 7;                  // XCD-constant per b
    const int ch  = blk >> 3;                 // 0..63

    const int tid  = threadIdx.x;
    const int wave = tid >> 6;
    const int lane = tid & 63;
    const int l16  = lane & 15;
    const int quad = lane >> 4;

    const int c0 = ch * CSLAB;

    __shared__ __align__(16) float xs[2][KC][NN];   // 2 x 32 KB

    const float* Xbase = X + ((size_t)b * NHW + c0) * NN;   // row r = c0+r
    const float* Tp0   = T + ((size_t)b * NM + l16) * NHW + c0 + quad * 8;
    const float* Tp1   = Tp0 + (size_t)16 * NHW;

    // Rotated column index for this lane's reads (rows quad*8+j -> rot=8*quad).
    // Loop-invariant: hoisted out of the K loop entirely.
    const int col0 = ((wave << 5) + l16 + (quad << 3)) & 255;          // f=0
    const int col1 = (col0 + 16) & 255;                                 // f=1

    // Prologue: stage slab 0 (wave w stages rows w, w+8, w+16, w+24)
#pragma unroll
    for (int r = 0; r < 4; ++r) {
        const int row = wave + r * 8;
        stage_row(Xbase + (size_t)row * NN, &xs[0][row][0], lane, r << 3);
    }

    f32x4 ax0[2], ax1[2], as0[2], as1[2];
#pragma unroll
    for (int f = 0; f < 2; ++f) {
        ax0[f] = f32x4{0.f, 0.f, 0.f, 0.f};
        ax1[f] = f32x4{0.f, 0.f, 0.f, 0.f};
        as0[f] = f32x4{0.f, 0.f, 0.f, 0.f};
        as1[f] = f32x4{0.f, 0.f, 0.f, 0.f};
    }
    float sneg[2] = {0.f, 0.f};
    float ssig[2] = {0.f, 0.f};
    float ts0 = 0.f, ts1 = 0.f;

    for (int ks = 0; ks < KSTEPS; ++ks) {
        __syncthreads();                       // xs[ks&1] staged (drains vmcnt)
        const int nb = ks + 1;
        if (nb < KSTEPS) {                     // stage next slab while computing
            const float* Xn = Xbase + (size_t)nb * KC * NN;
#pragma unroll
            for (int r = 0; r < 4; ++r) {
                const int row = wave + r * 8;
                stage_row(Xn + (size_t)row * NN, &xs[nb & 1][row][0], lane, r << 3);
            }
        }

        // B fragments: direct global float4 (same lines for all 8 waves -> L1/L2)
        float4 ta = *(const float4*)(Tp0 + ks * KC);
        float4 tb = *(const float4*)(Tp0 + ks * KC + 4);
        float4 tc = *(const float4*)(Tp1 + ks * KC);
        float4 td = *(const float4*)(Tp1 + ks * KC + 4);
        half8 ht0 = {(_Float16)ta.x, (_Float16)ta.y, (_Float16)ta.z, (_Float16)ta.w,
                     (_Float16)tb.x, (_Float16)tb.y, (_Float16)tb.z, (_Float16)tb.w};
        half8 ht1 = {(_Float16)tc.x, (_Float16)tc.y, (_Float16)tc.z, (_Float16)tc.w,
                     (_Float16)td.x, (_Float16)td.y, (_Float16)td.z, (_Float16)td.w};
        ts0 += (ta.x + ta.y) + (ta.z + ta.w) + (tb.x + tb.y) + (tb.z + tb.w);
        ts1 += (tc.x + tc.y) + (tc.z + tc.w) + (td.x + td.y) + (td.z + td.w);

#pragma unroll
        for (int f = 0; f < 2; ++f) {
            const int colf = f ? col1 : col0;
            float xv[8];
#pragma unroll
            for (int j = 0; j < 8; ++j)
                xv[j] = xs[ks & 1][quad * 8 + j][colf];
            half8 hx, hs;
#pragma unroll
            for (int j = 0; j < 8; ++j) {
                float x = xv[j];
                float e = __expf(-fabsf(x));                    // exp(-|x|) <= 1
                float rc = __builtin_amdgcn_rcpf(1.f + e);
                float s  = (x >= 0.f) ? rc : 1.f - rc;          // stable sigmoid
                float pos = fmaxf(-x, 0.f) + __logf(1.f + e);   // softplus(-x)
                sneg[f] += x + pos;
                ssig[f] += s;
                hx[j] = (_Float16)x;
                hs[j] = (_Float16)s;
            }
            ax0[f] = MFMA16(hx, ht0, ax0[f]);
            ax1[f] = MFMA16(hx, ht1, ax1[f]);
            as0[f] = MFMA16(hs, ht0, as0[f]);
            as1[f] = MFMA16(hs, ht1, as1[f]);
        }
    }

    // ---- epilogue: wave-exclusive n-stripes -> plain stores, no reduction ----
#pragma unroll
    for (int f = 0; f < 2; ++f) {
        float sn = sneg[f], ss = ssig[f];     // 4 quads share n -> quad-reduce
        sn += __shfl_xor(sn, 16); sn += __shfl_xor(sn, 32);
        ss += __shfl_xor(ss, 16); ss += __shfl_xor(ss, 32);
        if (lane < 16) {
            const size_t sb = ((size_t)ch * NB + b) * NN + wave * 32 + f * 16 + l16;
            ws[OFF_SNP + sb] = sn;
            ws[OFF_SSP + sb] = ss;
        }
    }
    if (wave == 0) {                           // all waves computed identical ts
        float t0 = ts0, t1 = ts1;
        t0 += __shfl_xor(t0, 16); t0 += __shfl_xor(t0, 32);
        t1 += __shfl_xor(t1, 16); t1 += __shfl_xor(t1, 32);
        if (lane < 16) {
            const size_t tb_ = ((size_t)ch * NB + b) * NM;
            ws[OFF_STGT + tb_ + l16]      = t0;
            ws[OFF_STGT + tb_ + l16 + 16] = t1;
        }
    }
    const size_t dbase = ((size_t)ch * NB + b) * NN * NM;
#pragma unroll
    for (int f = 0; f < 2; ++f) {
#pragma unroll
        for (int r = 0; r < 4; ++r) {
            const int n = wave * 32 + f * 16 + quad * 4 + r;
            const size_t o = dbase + (size_t)n * NM;
            ws[OFF_DXP + o + l16]      = ax0[f][r];
            ws[OFF_DXP + o + l16 + 16] = ax1[f][r];
            ws[OFF_DSP + o + l16]      = as0[f][r];
            ws[OFF_DSP + o + l16 + 16] = as1[f][r];
        }
    }
}

// ---------------------------------------------------------------------------
// Combine 64 chunk partials + class/center/dice formula.
// REWRITE: one block per (b,n) -> 2048 blocks (8/CU, 32 waves/CU), 8-way
// split of the ch-reduction across thread groups + LDS tree.  The old
// version (256 blocks, 1/CU, 64 strided gather iters/thread) was
// latency-bound at ~4 waves/CU.
__global__ __launch_bounds__(256) void cost_finalize(
    const float* __restrict__ P,    // [NB][NN][1]
    const float* __restrict__ CD,   // [NB][NN][NM]
    const int*   __restrict__ LAB,  // [NB][NM]
    const float* __restrict__ ws,
    float* __restrict__ out) {
    const int bn = blockIdx.x;            // b*NN + n
    const int n  = bn & 255;
    const int b  = bn >> 8;
    const int t  = threadIdx.x;
    const int m  = t & 31;
    const int q  = t >> 5;                // 0..7 : ch octet

    float dx = 0.f, ds = 0.f, sn = 0.f, ss = 0.f, st = 0.f;
#pragma unroll
    for (int k = 0; k < 8; ++k) {
        const int ch = q * 8 + k;
        const size_t e = (size_t)ch * NB + b;
        const size_t o = (e * NN + n) * NM + m;
        dx += ws[OFF_DXP + o];
        ds += ws[OFF_DSP + o];
        sn += ws[OFF_SNP + e * NN + n];
        ss += ws[OFF_SSP + e * NN + n];
        st += ws[OFF_STGT + e * NM + m];
    }

    __shared__ float red[5][8][32];
    red[0][q][m] = dx; red[1][q][m] = ds; red[2][q][m] = sn;
    red[3][q][m] = ss; red[4][q][m] = st;
    __syncthreads();

    if (t < 32) {                          // t == m here
        float a0 = 0.f, a1 = 0.f, a2 = 0.f, a3 = 0.f, a4 = 0.f;
#pragma unroll
        for (int k = 0; k < 8; ++k) {
            a0 += red[0][k][m]; a1 += red[1][k][m]; a2 += red[2][k][m];
            a3 += red[3][k][m]; a4 += red[4][k][m];
        }
        const float p   = P[bn];
        const int   lab = LAB[b * NM + m];
        const float cls = lab ? -p : (p - 1.f);

        const float cmask = (a2 - a0) * (1.f / (float)NHW);
        const float dice  = 1.f - (2.f * a1 + 1.f) / (a3 + a4 + 1.f);

        const size_t o = (size_t)bn * NM + m;
        out[o] = 2.f * cls + CD[o] + 5.f * cmask + 2.f * dice;
    }
}

// ---------------------------------------------------------------------------
extern "C" void kernel_launch(void* const* d_in, const int* in_sizes, int n_in,
                              void* d_out, int out_size, void* d_ws, size_t ws_size,
                              hipStream_t stream) {
    const float* P   = (const float*)d_in[0];  // sem_cls_prob
    const float* CD  = (const float*)d_in[1];  // center_dist
    const float* X   = (const float*)d_in[2];  // mask_heatmaps
    const float* T   = (const float*)d_in[3];  // mask_tgt
    const int*   LAB = (const int*)d_in[4];    // gt_plane_sem_cls_label
    float* out = (float*)d_out;
    float* ws  = (float*)d_ws;

    hipLaunchKernelGGL(cost_main, dim3(NB * CCH), dim3(512), 0, stream, X, T, ws);
    hipLaunchKernelGGL(cost_finalize, dim3(NB * NN), dim3(256), 0, stream,
                       P, CD, LAB, ws, out);
}